// Round 1
// baseline (11.476 us; speedup 1.0000x reference)
//
#include <hip/hip_runtime.h>
#include <hip/hip_bf16.h>

// Tropical linear: out[r,o] = logsumexp_i(x[r,i] + w[i,o])
//                = m_r + log( sum_i exp(x[r,i]-m_r) * exp(w[i,o]) )
// => bf16 MFMA GEMM [16384x128]x[128x128] with exp/log pre/post-processing.

using bf16x8 = __attribute__((ext_vector_type(8))) short;   // 8 bf16 = 4 VGPRs
using f32x4  = __attribute__((ext_vector_type(4))) float;   // MFMA accumulator

__device__ __forceinline__ unsigned short f2bf(float v) {
    __hip_bfloat16 b = __float2bfloat16(v);
    return __builtin_bit_cast(unsigned short, b);
}

__global__ __launch_bounds__(512) void trop_kernel(const float* __restrict__ x,
                                                   const float* __restrict__ w,
                                                   float* __restrict__ out) {
    // B(=exp(w)) in MFMA-fragment-contiguous layout:
    // frag f = c*4 + kb  (c: 16-col group 0..7, kb: 32-k group 0..3)
    // slot L (=reader lane): holds B[kb*32 + (L>>4)*8 + e][c*16 + (L&15)], e=0..7 (16B)
    __shared__ uint4 ewl[2048];  // 32 frags * 64 lanes * 16B = 32 KiB

    const int tid  = threadIdx.x;
    const int lane = tid & 63;
    const int wv   = tid >> 6;      // 0..7
    const int R    = wv >> 1;       // row strip 0..3
    const int Cs   = wv & 1;        // col half 0..1
    const int r16  = lane & 15;
    const int g    = lane >> 4;     // 0..3

    const int r0   = blockIdx.x * 64 + R * 16;   // wave's first row
    const int grow = r0 + r16;                   // this lane's A row

    // ---- issue A (x) loads first: lane's 32 elements, k = kb*32 + g*8 + {0..7} ----
    const float* xp = x + (size_t)grow * 128 + g * 8;
    float4 xv[8];
#pragma unroll
    for (int kb = 0; kb < 4; ++kb) {
#pragma unroll
        for (int h = 0; h < 2; ++h)
            xv[kb * 2 + h] = *reinterpret_cast<const float4*>(xp + kb * 32 + h * 4);
    }

    // ---- phase 1: Ew = exp(w) -> LDS fragments (each w element touched once) ----
#pragma unroll
    for (int r = 0; r < 4; ++r) {
        int s  = r * 512 + tid;      // slot 0..2047
        int f  = s >> 6;             // frag 0..31
        int L  = s & 63;             // lane-in-frag
        int kb = f & 3;
        int c  = f >> 2;
        int o  = c * 16 + (L & 15);
        const float* wp = w + (size_t)(kb * 32 + (L >> 4) * 8) * 128 + o;
        unsigned int pk[4];
#pragma unroll
        for (int e = 0; e < 4; ++e) {
            unsigned short lo = f2bf(__expf(wp[(2 * e)     * 128]));
            unsigned short hi = f2bf(__expf(wp[(2 * e + 1) * 128]));
            pk[e] = (unsigned int)lo | ((unsigned int)hi << 16);
        }
        ewl[f * 64 + L] = make_uint4(pk[0], pk[1], pk[2], pk[3]);
    }

    // ---- A prep (registers only): row max via 4-lane reduce, exp, pack bf16 ----
    float mx = -3.4e38f;
#pragma unroll
    for (int i = 0; i < 8; ++i) {
        float4 v = xv[i];
        mx = fmaxf(mx, fmaxf(fmaxf(v.x, v.y), fmaxf(v.z, v.w)));
    }
    mx = fmaxf(mx, __shfl_xor(mx, 16, 64));
    mx = fmaxf(mx, __shfl_xor(mx, 32, 64));   // lanes {r,r+16,r+32,r+48} share row r

    bf16x8 afrag[4];
#pragma unroll
    for (int kb = 0; kb < 4; ++kb) {
#pragma unroll
        for (int h = 0; h < 2; ++h) {
            float4 v = xv[kb * 2 + h];
            afrag[kb][h * 4 + 0] = (short)f2bf(__expf(v.x - mx));
            afrag[kb][h * 4 + 1] = (short)f2bf(__expf(v.y - mx));
            afrag[kb][h * 4 + 2] = (short)f2bf(__expf(v.z - mx));
            afrag[kb][h * 4 + 3] = (short)f2bf(__expf(v.w - mx));
        }
    }

    __syncthreads();

    // ---- GEMM: 16 x v_mfma_f32_16x16x32_bf16 per wave (16 rows x 64 cols, K=128) ----
    f32x4 acc[4] = {};
#pragma unroll
    for (int kb = 0; kb < 4; ++kb) {
#pragma unroll
        for (int cc = 0; cc < 4; ++cc) {
            int f = (Cs * 4 + cc) * 4 + kb;
            bf16x8 b = *reinterpret_cast<const bf16x8*>(&ewl[f * 64 + lane]);
            acc[cc] = __builtin_amdgcn_mfma_f32_16x16x32_bf16(afrag[kb], b, acc[cc], 0, 0, 0);
        }
    }

    // ---- epilogue: out = m_row + log(sum). C/D: col = lane&15, row = g*4 + reg ----
    float mrow[4];
#pragma unroll
    for (int q = 0; q < 4; ++q) mrow[q] = __shfl(mx, g * 4 + q, 64);  // m of row r0+g*4+q

#pragma unroll
    for (int cc = 0; cc < 4; ++cc) {
        int col = Cs * 64 + cc * 16 + r16;
        float* op = out + (size_t)(r0 + g * 4) * 128 + col;
#pragma unroll
        for (int q = 0; q < 4; ++q)
            op[(size_t)q * 128] = mrow[q] + __logf(acc[cc][q]);
    }
}

extern "C" void kernel_launch(void* const* d_in, const int* in_sizes, int n_in,
                              void* d_out, int out_size, void* d_ws, size_t ws_size,
                              hipStream_t stream) {
    const float* x = (const float*)d_in[0];   // [8,2048,128] fp32
    const float* w = (const float*)d_in[1];   // [128,128] fp32
    float* out = (float*)d_out;               // [8,2048,128] fp32
    // 16384 rows / 64 rows-per-block = 256 blocks (1 per CU), 512 threads (8 waves)
    trop_kernel<<<256, 512, 0, stream>>>(x, w, out);
}